// Round 3
// baseline (1257.607 us; speedup 1.0000x reference)
//
#include <hip/hip_runtime.h>
#include <hip/hip_fp16.h>
#include <math.h>

// Problem constants (from reference)
#define BS    8
#define NE    4800
#define NN    4981
#define CIN   3
#define HD    128      // H
#define DBLK  6        // D processor blocks
#define NEDGE 153600   // BS*EPG
#define NTOT  38400    // BS*NE (graph nodes)
#define NMESH (BS*NN)  // 39848 mesh rows

typedef _Float16 f16;
typedef _Float16 f16x8 __attribute__((ext_vector_type(8)));
typedef float f32x4 __attribute__((ext_vector_type(4)));

__device__ __forceinline__ float lrelu(float x) { return x >= 0.0f ? x : 0.2f * x; }

// ---------------------------------------------------------------------------
// K0: hv0 = ln(mlp(enc_clnb_row, enc_ew1..3), enc_elng, enc_elnb)
// Conv encoder + LayerNorm over size-1 axis collapses exactly to enc_clnb.
// ---------------------------------------------------------------------------
__global__ __launch_bounds__(128)
void enc_const_kernel(const float* __restrict__ clnb,
                      const float* __restrict__ ew1, const float* __restrict__ eb1,
                      const float* __restrict__ ew2, const float* __restrict__ eb2,
                      const float* __restrict__ ew3,
                      const float* __restrict__ g, const float* __restrict__ b,
                      float* __restrict__ hv0) {
    __shared__ float s1[HD], s2[HD], s3[HD];
    int j = threadIdx.x;
    float a = eb1[j];
    for (int c = 0; c < CIN; ++c) a += clnb[c] * ew1[c * HD + j];
    s1[j] = lrelu(a);
    __syncthreads();
    a = eb2[j];
    for (int k = 0; k < HD; ++k) a += s1[k] * ew2[k * HD + j];
    s2[j] = lrelu(a);
    __syncthreads();
    a = 0.0f;
    for (int k = 0; k < HD; ++k) a += s2[k] * ew3[k * HD + j];
    s3[j] = a;
    __syncthreads();
    float m = 0.0f;
    for (int k = 0; k < HD; ++k) m += s3[k];
    m *= (1.0f / HD);
    float v = 0.0f;
    for (int k = 0; k < HD; ++k) { float d = s3[k] - m; v += d * d; }
    v *= (1.0f / HD);
    float rs = 1.0f / sqrtf(v + 1e-5f);
    hv0[j] = (s3[j] - m) * rs * g[j] + b[j];
}

// Broadcast hv0 (fp32) to all NTOT node rows as f16
__global__ __launch_bounds__(256)
void init_h16_kernel(f16* __restrict__ h, const float* __restrict__ hv0, int n8) {
    __shared__ f16 v[HD];
    if (threadIdx.x < HD) v[threadIdx.x] = (f16)hv0[threadIdx.x];
    __syncthreads();
    for (int i = blockIdx.x * blockDim.x + threadIdx.x; i < n8; i += gridDim.x * blockDim.x)
        ((uint4*)h)[i] = ((const uint4*)v)[i & 15];
}

// ---------------------------------------------------------------------------
// Convert + transpose processor weights to f16 Wt[n][k] layout.
// 48 matrices of 128x128: per d: eW1a,eW1b,eW2,eW3,nW1a,nW1b,nW2,nW3
// ---------------------------------------------------------------------------
__global__ __launch_bounds__(256)
void conv_weights_kernel(const float* __restrict__ ew1, const float* __restrict__ ew2,
                         const float* __restrict__ ew3,
                         const float* __restrict__ nw1, const float* __restrict__ nw2,
                         const float* __restrict__ nw3, f16* __restrict__ wbuf) {
    int b = blockIdx.x;        // 0..47
    int d = b >> 3, m = b & 7;
    const float* src;
    switch (m) {
        case 0: src = ew1 + (size_t)d * 2 * HD * HD; break;
        case 1: src = ew1 + (size_t)d * 2 * HD * HD + HD * HD; break;
        case 2: src = ew2 + (size_t)d * HD * HD; break;
        case 3: src = ew3 + (size_t)d * HD * HD; break;
        case 4: src = nw1 + (size_t)d * 2 * HD * HD; break;
        case 5: src = nw1 + (size_t)d * 2 * HD * HD + HD * HD; break;
        case 6: src = nw2 + (size_t)d * HD * HD; break;
        default: src = nw3 + (size_t)d * HD * HD; break;
    }
    f16* out = wbuf + (size_t)b * HD * HD;
    for (int idx = threadIdx.x; idx < HD * HD; idx += 256) {
        int n = idx >> 7, k = idx & 127;
        out[idx] = (f16)src[k * HD + n];   // Wt[n][k] = W[k][n]
    }
}

// ---------------------------------------------------------------------------
// Fused GraphNet MLP tile kernel on MFMA (fp16 in, fp32 accumulate).
// B-fragments load DIRECTLY from global (Wt[n][k] rows are L1/L2-resident;
// per-lane fragment = 16 contiguous bytes) -> no weight LDS staging, no
// staging barriers, no bank conflicts. LDS = As1+As2 only (~36 KB) -> 4
// blocks/CU.
// MODE 0 = edge: A1=h[dest], A2=h[src]; LN out -> packed-f16 atomics to aggr.
// MODE 1 = node: A1=h[row],  A2=aggr16[row]; LN out -> h_out f16.
// Tile 64 rows x 128 cols, 4 waves; wave w: rows (w>>1)*32, cols (w&1)*64,
// 2x4 grid of 16x16x32 MFMA. A[m=lane&15][k=quad*8+j], C/D col=lane&15,
// row=quad*4+reg (guide-verified).
// ---------------------------------------------------------------------------
__device__ __forceinline__ void gemm_k128_g(const f16 (*A)[HD + 8], const f16* __restrict__ Wg,
                                            int rt_base, int ct_base, int ln, int quad,
                                            f32x4 acc[2][4]) {
    #pragma unroll
    for (int ks = 0; ks < 4; ++ks) {
        int kb = ks * 32 + quad * 8;
        f16x8 a0 = *(const f16x8*)(&A[rt_base + ln][kb]);
        f16x8 a1 = *(const f16x8*)(&A[rt_base + 16 + ln][kb]);
        #pragma unroll
        for (int c = 0; c < 4; ++c) {
            f16x8 b = *(const f16x8*)(Wg + (size_t)(ct_base + c * 16 + ln) * HD + kb);
            acc[0][c] = __builtin_amdgcn_mfma_f32_16x16x32_f16(a0, b, acc[0][c], 0, 0, 0);
            acc[1][c] = __builtin_amdgcn_mfma_f32_16x16x32_f16(a1, b, acc[1][c], 0, 0, 0);
        }
    }
}

template <int MODE>
__global__ __launch_bounds__(256, 4)
void gn_mfma(const f16* __restrict__ h16, const f16* __restrict__ aggr_in,
             const int* __restrict__ dest, const int* __restrict__ src,
             const f16* __restrict__ W1a, const f16* __restrict__ W1b,
             const f16* __restrict__ W2, const f16* __restrict__ W3,
             const float* __restrict__ b1, const float* __restrict__ b2,
             const float* __restrict__ g, const float* __restrict__ bln,
             f16* __restrict__ aggr_out, f16* __restrict__ h_out) {
    __shared__ __align__(16) f16 As1[64][HD + 8];
    __shared__ __align__(16) f16 As2[64][HD + 8];
    __shared__ float red[64][2][2];
    __shared__ int dS[64], sS[64];

    const int tid = threadIdx.x;
    const int base = blockIdx.x * 64;
    const int wave = tid >> 6;
    const int lane = tid & 63;
    const int ln = lane & 15;
    const int quad = lane >> 4;
    const int rt_base = (wave >> 1) * 32;
    const int ct_base = (wave & 1) * 64;
    const int half = wave & 1;

    if (MODE == 0) {
        if (tid < 64) dS[tid] = dest[base + tid];
        else if (tid < 128) sS[tid - 64] = src[base + tid - 64];
        __syncthreads();
    }

    // ---- Stage A tiles (f16, 16B chunks: 64 rows x 16 chunks per tile)
    #pragma unroll
    for (int t = 0; t < 4; ++t) {
        int idx = tid + t * 256;            // 0..1023
        int r = idx >> 4, c = (idx & 15) * 8;
        if (MODE == 0) {
            *(uint4*)(&As1[r][c]) = *(const uint4*)(h16 + (size_t)dS[r] * HD + c);
            *(uint4*)(&As2[r][c]) = *(const uint4*)(h16 + (size_t)sS[r] * HD + c);
        } else {
            *(uint4*)(&As1[r][c]) = *(const uint4*)(h16 + (size_t)(base + r) * HD + c);
            *(uint4*)(&As2[r][c]) = *(const uint4*)(aggr_in + (size_t)(base + r) * HD + c);
        }
    }
    __syncthreads();

    f32x4 acc[2][4];

    // ---- Layer 1: K=256 over [As1 | As2], bias b1, lrelu
    #pragma unroll
    for (int c = 0; c < 4; ++c) {
        float bj = b1[ct_base + c * 16 + ln];
        f32x4 bb = {bj, bj, bj, bj};
        acc[0][c] = bb; acc[1][c] = bb;
    }
    gemm_k128_g(As1, W1a, rt_base, ct_base, ln, quad, acc);
    gemm_k128_g(As2, W1b, rt_base, ct_base, ln, quad, acc);
    __syncthreads();          // all As1/As2 reads done
    #pragma unroll
    for (int i = 0; i < 2; ++i)
        #pragma unroll
        for (int c = 0; c < 4; ++c)
            #pragma unroll
            for (int r = 0; r < 4; ++r)
                As1[rt_base + i * 16 + quad * 4 + r][ct_base + c * 16 + ln] =
                    (f16)lrelu(acc[i][c][r]);
    __syncthreads();          // act1 visible

    // ---- Layer 2: K=128 over As1, bias b2, lrelu
    #pragma unroll
    for (int c = 0; c < 4; ++c) {
        float bj = b2[ct_base + c * 16 + ln];
        f32x4 bb = {bj, bj, bj, bj};
        acc[0][c] = bb; acc[1][c] = bb;
    }
    gemm_k128_g(As1, W2, rt_base, ct_base, ln, quad, acc);
    // no barrier needed before writing As2: its last readers (L1) are fenced,
    // and concurrent L2 readers touch only As1.
    #pragma unroll
    for (int i = 0; i < 2; ++i)
        #pragma unroll
        for (int c = 0; c < 4; ++c)
            #pragma unroll
            for (int r = 0; r < 4; ++r)
                As2[rt_base + i * 16 + quad * 4 + r][ct_base + c * 16 + ln] =
                    (f16)lrelu(acc[i][c][r]);
    __syncthreads();          // act2 visible (also fences stragglers' As1 reads)

    // ---- Layer 3: K=128 over As2, no bias/activation
    #pragma unroll
    for (int c = 0; c < 4; ++c) {
        f32x4 z = {0.f, 0.f, 0.f, 0.f};
        acc[0][c] = z; acc[1][c] = z;
    }
    gemm_k128_g(As2, W3, rt_base, ct_base, ln, quad, acc);

    // ---- LayerNorm stats: quad-level shfl reduce (lanes of a quad are
    // contiguous -> xor masks 1,2,4,8 stay in-quad), combine wave halves in LDS
    #pragma unroll
    for (int i = 0; i < 2; ++i)
        #pragma unroll
        for (int r = 0; r < 4; ++r) {
            float s = acc[i][0][r] + acc[i][1][r] + acc[i][2][r] + acc[i][3][r];
            float q = acc[i][0][r] * acc[i][0][r] + acc[i][1][r] * acc[i][1][r] +
                      acc[i][2][r] * acc[i][2][r] + acc[i][3][r] * acc[i][3][r];
            s += __shfl_xor(s, 1); q += __shfl_xor(q, 1);
            s += __shfl_xor(s, 2); q += __shfl_xor(q, 2);
            s += __shfl_xor(s, 4); q += __shfl_xor(q, 4);
            s += __shfl_xor(s, 8); q += __shfl_xor(q, 8);
            if (ln == 0) {
                int row = rt_base + i * 16 + quad * 4 + r;
                red[row][half][0] = s;
                red[row][half][1] = q;
            }
        }
    __syncthreads();

    // ---- Epilogue: LN scale + packed-f16 atomics (edge) or f16 store (node)
    float gv[4], bv[4];
    #pragma unroll
    for (int c = 0; c < 4; ++c) {
        int col = ct_base + c * 16 + ln;
        gv[c] = g[col]; bv[c] = bln[col];
    }
    #pragma unroll
    for (int i = 0; i < 2; ++i)
        #pragma unroll
        for (int r = 0; r < 4; ++r) {
            int row = rt_base + i * 16 + quad * 4 + r;
            float s = red[row][0][0] + red[row][1][0];
            float q = red[row][0][1] + red[row][1][1];
            float m = s * (1.0f / HD);
            float var = q * (1.0f / HD) - m * m;
            float rs = 1.0f / sqrtf(var + 1e-5f);
            #pragma unroll
            for (int c = 0; c < 4; ++c) {
                int col = ct_base + c * 16 + ln;
                float v = (acc[i][c][r] - m) * rs * gv[c] + bv[c];
                if (MODE == 0) {
                    float pv = __shfl_xor(v, 1);   // partner col (ln^1)
                    if (!(ln & 1)) {
                        __half2 h2 = __floats2half2_rn(v, pv);
                        unsafeAtomicAdd((__half2*)(aggr_out + (size_t)dS[row] * HD + col),
                                        h2);
                    }
                } else {
                    h_out[(size_t)(base + row) * HD + col] = (f16)v;
                }
            }
        }
}

// ---------------------------------------------------------------------------
// Decoder stage 1: per-channel upsample 1->4 + LN(4) + scatter-add to mesh.
// Flat: one thread per (element, channel).
// ---------------------------------------------------------------------------
__global__ __launch_bounds__(256)
void dec_up_kernel(const f16* __restrict__ h, const int* __restrict__ conn,
                   const float* __restrict__ uw1, const float* __restrict__ ub1,
                   const float* __restrict__ uw2, const float* __restrict__ ub2,
                   const float* __restrict__ uw3,
                   const float* __restrict__ ulng, const float* __restrict__ ulnb,
                   float* __restrict__ outn) {
    int idx = blockIdx.x * 256 + threadIdx.x;    // 0 .. NTOT*HD-1
    int n = idx >> 7, c = idx & 127;
    int b = n / NE, e = n - b * NE;
    float s = (float)h[idx];
    float u1[4], u2[4], u3[4];
    #pragma unroll
    for (int o = 0; o < 4; ++o) u1[o] = lrelu(s * uw1[c * 4 + o] + ub1[c * 4 + o]);
    #pragma unroll
    for (int o = 0; o < 4; ++o) {
        float a = ub2[c * 4 + o];
        #pragma unroll
        for (int i = 0; i < 4; ++i) a += u1[i] * uw2[c * 16 + i * 4 + o];
        u2[o] = lrelu(a);
    }
    #pragma unroll
    for (int o = 0; o < 4; ++o) {
        float a = 0.f;
        #pragma unroll
        for (int i = 0; i < 4; ++i) a += u2[i] * uw3[c * 16 + i * 4 + o];
        u3[o] = a;
    }
    float m = 0.25f * (u3[0] + u3[1] + u3[2] + u3[3]);
    float var = 0.f;
    #pragma unroll
    for (int o = 0; o < 4; ++o) { float d = u3[o] - m; var += d * d; }
    var *= 0.25f;
    float rs = 1.0f / sqrtf(var + 1e-5f);
    #pragma unroll
    for (int o = 0; o < 4; ++o) {
        float val = (u3[o] - m) * rs * ulng[c * 4 + o] + ulnb[c * 4 + o];
        int nd = conn[e * 4 + o];
        unsafeAtomicAdd(&outn[((size_t)b * NN + nd) * HD + c], val);
    }
}

// ---------------------------------------------------------------------------
// Decoder stage 2: per mesh row H->3->3->3, one wave per row
// ---------------------------------------------------------------------------
__global__ __launch_bounds__(256)
void dec_out_kernel(const float* __restrict__ outn,
                    const float* __restrict__ cw1, const float* __restrict__ cb1,
                    const float* __restrict__ cw2, const float* __restrict__ cb2,
                    const float* __restrict__ cw3,
                    float* __restrict__ o, int nrows) {
    int r = blockIdx.x * 4 + (threadIdx.x >> 6);
    if (r >= nrows) return;
    int lane = threadIdx.x & 63;
    float v1 = outn[(size_t)r * HD + lane];
    float v2 = outn[(size_t)r * HD + 64 + lane];
    float s[3];
    #pragma unroll
    for (int c = 0; c < 3; ++c)
        s[c] = v1 * cw1[lane * 3 + c] + v2 * cw1[(lane + 64) * 3 + c];
    #pragma unroll
    for (int off = 32; off >= 1; off >>= 1) {
        s[0] += __shfl_down(s[0], off);
        s[1] += __shfl_down(s[1], off);
        s[2] += __shfl_down(s[2], off);
    }
    if (lane == 0) {
        float t1[3], t2[3];
        #pragma unroll
        for (int c = 0; c < 3; ++c) t1[c] = lrelu(s[c] + cb1[c]);
        #pragma unroll
        for (int c = 0; c < 3; ++c) {
            float a = cb2[c];
            #pragma unroll
            for (int k = 0; k < 3; ++k) a += t1[k] * cw2[k * 3 + c];
            t2[c] = lrelu(a);
        }
        #pragma unroll
        for (int c = 0; c < 3; ++c) {
            float a = 0.f;
            #pragma unroll
            for (int k = 0; k < 3; ++k) a += t2[k] * cw3[k * 3 + c];
            o[(size_t)r * 3 + c] = a;
        }
    }
}

// ---------------------------------------------------------------------------
extern "C" void kernel_launch(void* const* d_in, const int* in_sizes, int n_in,
                              void* d_out, int out_size, void* d_ws, size_t ws_size,
                              hipStream_t stream) {
    const int* elem_conn = (const int*)d_in[1];
    const int* edge_index = (const int*)d_in[2];
    const int* e_src = edge_index;          // row 0
    const int* e_dst = edge_index + NEDGE;  // row 1
    const float* enc_clnb = (const float*)d_in[9];
    const float* enc_ew1 = (const float*)d_in[10];
    const float* enc_eb1 = (const float*)d_in[11];
    const float* enc_ew2 = (const float*)d_in[12];
    const float* enc_eb2 = (const float*)d_in[13];
    const float* enc_ew3 = (const float*)d_in[14];
    const float* enc_elng = (const float*)d_in[15];
    const float* enc_elnb = (const float*)d_in[16];
    const float* p_ew1 = (const float*)d_in[17];
    const float* p_eb1 = (const float*)d_in[18];
    const float* p_ew2 = (const float*)d_in[19];
    const float* p_eb2 = (const float*)d_in[20];
    const float* p_ew3 = (const float*)d_in[21];
    const float* p_elng = (const float*)d_in[22];
    const float* p_elnb = (const float*)d_in[23];
    const float* p_nw1 = (const float*)d_in[24];
    const float* p_nb1 = (const float*)d_in[25];
    const float* p_nw2 = (const float*)d_in[26];
    const float* p_nb2 = (const float*)d_in[27];
    const float* p_nw3 = (const float*)d_in[28];
    const float* p_nlng = (const float*)d_in[29];
    const float* p_nlnb = (const float*)d_in[30];
    const float* dec_uw1 = (const float*)d_in[31];
    const float* dec_ub1 = (const float*)d_in[32];
    const float* dec_uw2 = (const float*)d_in[33];
    const float* dec_ub2 = (const float*)d_in[34];
    const float* dec_uw3 = (const float*)d_in[35];
    const float* dec_ulng = (const float*)d_in[36];
    const float* dec_ulnb = (const float*)d_in[37];
    const float* dec_cw1 = (const float*)d_in[38];
    const float* dec_cb1 = (const float*)d_in[39];
    const float* dec_cw2 = (const float*)d_in[40];
    const float* dec_cb2 = (const float*)d_in[41];
    const float* dec_cw3 = (const float*)d_in[42];

    // Workspace layout (bytes):
    //   hA16 9.83MB | hB16 9.83MB | wbuf 1.57MB | hv0 512B | aggr16/outn 20.4MB
    // aggr16 (f16 NTOT*HD) and outn (fp32 NMESH*HD) share the last region.
    char* ws = (char*)d_ws;
    f16* hA16 = (f16*)(ws);
    f16* hB16 = (f16*)(ws + 9830400);
    f16* wbuf = (f16*)(ws + 19660800);
    float* hv0 = (float*)(ws + 21233664);
    f16* aggr16 = (f16*)(ws + 21234176);
    float* outn = (float*)(ws + 21234176);

    enc_const_kernel<<<1, 128, 0, stream>>>(enc_clnb, enc_ew1, enc_eb1, enc_ew2,
                                            enc_eb2, enc_ew3, enc_elng, enc_elnb, hv0);
    init_h16_kernel<<<1200, 256, 0, stream>>>(hA16, hv0, NTOT * HD / 8);
    conv_weights_kernel<<<48, 256, 0, stream>>>(p_ew1, p_ew2, p_ew3,
                                                p_nw1, p_nw2, p_nw3, wbuf);

    for (int d = 0; d < DBLK; ++d) {
        f16* cur = (d & 1) ? hB16 : hA16;
        f16* nxt = (d & 1) ? hA16 : hB16;
        const f16* ws_d = wbuf + (size_t)d * 8 * HD * HD;
        hipMemsetAsync(aggr16, 0, (size_t)NTOT * HD * sizeof(f16), stream);
        gn_mfma<0><<<NEDGE / 64, 256, 0, stream>>>(
            cur, nullptr, e_dst, e_src,
            ws_d + 0 * HD * HD, ws_d + 1 * HD * HD, ws_d + 2 * HD * HD, ws_d + 3 * HD * HD,
            p_eb1 + (size_t)d * HD, p_eb2 + (size_t)d * HD,
            p_elng + (size_t)d * HD, p_elnb + (size_t)d * HD,
            aggr16, nullptr);
        gn_mfma<1><<<NTOT / 64, 256, 0, stream>>>(
            cur, aggr16, nullptr, nullptr,
            ws_d + 4 * HD * HD, ws_d + 5 * HD * HD, ws_d + 6 * HD * HD, ws_d + 7 * HD * HD,
            p_nb1 + (size_t)d * HD, p_nb2 + (size_t)d * HD,
            p_nlng + (size_t)d * HD, p_nlnb + (size_t)d * HD,
            nullptr, nxt);
    }
    // after d=5, result is in hA16
    hipMemsetAsync(outn, 0, (size_t)NMESH * HD * sizeof(float), stream);
    dec_up_kernel<<<NTOT * HD / 256, 256, 0, stream>>>(hA16, elem_conn, dec_uw1, dec_ub1,
                                                       dec_uw2, dec_ub2, dec_uw3,
                                                       dec_ulng, dec_ulnb, outn);
    dec_out_kernel<<<(NMESH + 3) / 4, 256, 0, stream>>>(outn, dec_cw1, dec_cb1,
                                                        dec_cw2, dec_cb2, dec_cw3,
                                                        (float*)d_out, NMESH);
}